// Round 1
// baseline (374.150 us; speedup 1.0000x reference)
//
#include <hip/hip_runtime.h>

#define B 4
#define S 2048
#define H 16
#define DK 64
#define DM 1024
#define NTILES (S / 64)
#define QSCALE 0.18033688011112042f   // 0.125 * log2(e); folded into Q projection

typedef _Float16 half_t;
typedef __attribute__((ext_vector_type(8))) _Float16 half8v;   // 8 fp16 = MFMA A/B frag
typedef __attribute__((ext_vector_type(2))) __fp16   fp16x2;   // builtin return type
typedef __attribute__((ext_vector_type(4))) float    float4v;  // MFMA C/D frag

// pack two fp32 -> fp16x2 RTZ in one v_cvt_pkrtz (bias cancels in softmax O/l)
__device__ __forceinline__ unsigned pkh(float lo, float hi) {
    union { fp16x2 h; unsigned u; } cvt;
    cvt.h = __builtin_amdgcn_cvt_pkrtz(lo, hi);
    return cvt.u;
}
__device__ __forceinline__ float fast_exp2(float x) {
#if __has_builtin(__builtin_amdgcn_exp2f)
    return __builtin_amdgcn_exp2f(x);
#else
    return __expf(x * 0.69314718055994531f);
#endif
}
// convert 8 fp32 (two float4, consecutive k) -> fp16 frag (RNE v_cvt_f16_f32)
__device__ __forceinline__ half8v cvt8h(float4 a, float4 b) {
    half8v r;
    r[0] = (half_t)a.x; r[1] = (half_t)a.y; r[2] = (half_t)a.z; r[3] = (half_t)a.w;
    r[4] = (half_t)b.x; r[5] = (half_t)b.y; r[6] = (half_t)b.z; r[7] = (half_t)b.w;
    return r;
}
// async global -> LDS, 16B per lane. LDS dest = wave-uniform base + lane*16.
__device__ __forceinline__ void gl2lds16(const void* g, void* l) {
    __builtin_amdgcn_global_load_lds(
        (const __attribute__((address_space(1))) unsigned int*)g,
        (__attribute__((address_space(3))) unsigned int*)l, 16, 0, 0);
}

// ---------------------------------------------------------------------------
// Kernel 0: fused prep. Blocks [0, S*S/2048): expand mask int32 -> fp16 AND-
// words (0xFFFF keep / 0x0000 drop), laid out hm[q][k] so flash's packed-P
// mask application is a single v_and_b32 per u32.
// Blocks [+, +DM*DM/1024): convert Wo fp32 -> fp16.
// ---------------------------------------------------------------------------
#define HM_BLOCKS (S * S / 2048)
__global__ __launch_bounds__(256) void prep_kernel(
    const int* __restrict__ mask, unsigned short* __restrict__ hm,
    const float* __restrict__ Wo, half_t* __restrict__ Wh)
{
    int bx = blockIdx.x;
    if (bx < HM_BLOCKS) {
        int t = (bx * 256 + threadIdx.x) * 8;
        int4 m0 = *(const int4*)(mask + t);
        int4 m1 = *(const int4*)(mask + t + 4);
        uint4 w;
        w.x = (m0.x ? 0xFFFFu : 0u) | (m0.y ? 0xFFFF0000u : 0u);
        w.y = (m0.z ? 0xFFFFu : 0u) | (m0.w ? 0xFFFF0000u : 0u);
        w.z = (m1.x ? 0xFFFFu : 0u) | (m1.y ? 0xFFFF0000u : 0u);
        w.w = (m1.z ? 0xFFFFu : 0u) | (m1.w ? 0xFFFF0000u : 0u);
        *(uint4*)(hm + t) = w;
    } else {
        int t = ((bx - HM_BLOCKS) * 256 + threadIdx.x) * 4;
        float4 wv = *(const float4*)(Wo + t);
        union { half_t h[4]; uint2 u; } cvt;
        cvt.h[0] = (half_t)wv.x; cvt.h[1] = (half_t)wv.y;
        cvt.h[2] = (half_t)wv.z; cvt.h[3] = (half_t)wv.w;
        *(uint2*)(Wh + t) = cvt.u;
    }
}

// ---------------------------------------------------------------------------
// Kernel 1: QKV projection via fp16 MFMA. Output bounced through padded LDS
// tile (stride 72: 16B-aligned rows, bank-spread) -> two 16B global stores
// per lane instead of 16 scalar 2B stores.
// y=0: V -> Vt (B,H,64,S) with PV-permuted columns; y=1: K; y=2: Q (scaled).
// ---------------------------------------------------------------------------
#define QSTR 72   // LDS bounce-tile stride (halves): 144B rows, 16B aligned
__global__ __launch_bounds__(256) void qkv_proj_kernel(
    const float* __restrict__ xv, const float* __restrict__ xk, const float* __restrict__ xq,
    const float* __restrict__ Wv, const float* __restrict__ Wk, const float* __restrict__ Wq,
    half_t* __restrict__ vtw, half_t* __restrict__ kw, half_t* __restrict__ qw)
{
    __shared__ half_t Ls[64 * QSTR];

    const int y = blockIdx.y;
    const float* x; const float* W;
    if (y == 0)      { x = xv; W = Wv; }
    else if (y == 1) { x = xk; W = Wk; }
    else             { x = xq; W = Wq; }

    const int tid = threadIdx.x;
    const int w = tid >> 6, L = tid & 63, a = L & 15, g = L >> 4;
    const int bx  = blockIdx.x;
    const int st  = bx & 31;
    const int bh  = bx >> 5;
    const int b_  = bh >> 4, h = bh & 15;
    const int s0b = st * 64;

    // W fragments: lane a <-> dim-row 16t+a, quad g <-> k-chunk
    half8v wF[4][2];
    #pragma unroll
    for (int t = 0; t < 4; ++t)
        #pragma unroll
        for (int c = 0; c < 2; ++c) {
            const float* wr = W + (size_t)(16 * t + a) * 64 + 32 * c + 8 * g;
            wF[t][c] = cvt8h(*(const float4*)wr, *(const float4*)(wr + 4));
        }

    // x fragments: lane a <-> s-row s0b+16w+a
    const float* xr = x + ((size_t)(b_ * S) + s0b + 16 * w + a) * DM + h * 64 + 8 * g;
    half8v xF0 = cvt8h(*(const float4*)(xr),      *(const float4*)(xr + 4));
    half8v xF1 = cvt8h(*(const float4*)(xr + 32), *(const float4*)(xr + 36));

    const float4v z4 = {0.0f, 0.0f, 0.0f, 0.0f};

    if (y == 0) {
        // V^T: A = W (m=d), B = x (n=s). D[m=4g+r][n=a]. Ls[d][pos]
        const int c   = 16 * w + a;
        const int pos = 32 * (c >> 5) + 8 * ((c >> 2) & 3) + 4 * ((c >> 4) & 1) + (c & 3);
        #pragma unroll
        for (int mt = 0; mt < 4; ++mt) {
            float4v D = __builtin_amdgcn_mfma_f32_16x16x32_f16(wF[mt][0], xF0, z4, 0, 0, 0);
            D = __builtin_amdgcn_mfma_f32_16x16x32_f16(wF[mt][1], xF1, D, 0, 0, 0);
            #pragma unroll
            for (int r = 0; r < 4; ++r)
                Ls[(16 * mt + 4 * g + r) * QSTR + pos] = (half_t)D[r];
        }
    } else {
        const float scale = (y == 2) ? QSCALE : 1.0f;
        #pragma unroll
        for (int nt = 0; nt < 4; ++nt) {
            float4v D = __builtin_amdgcn_mfma_f32_16x16x32_f16(xF0, wF[nt][0], z4, 0, 0, 0);
            D = __builtin_amdgcn_mfma_f32_16x16x32_f16(xF1, wF[nt][1], D, 0, 0, 0);
            #pragma unroll
            for (int r = 0; r < 4; ++r)
                Ls[(16 * w + 4 * g + r) * QSTR + 16 * nt + a] = (half_t)(D[r] * scale);
        }
    }
    __syncthreads();

    // coalesced copy-out: each thread 16 halves (two 16B stores), 4 threads/row
    const int row = tid >> 2;
    const int col = (tid & 3) * 16;
    uint4 v0 = *(const uint4*)&Ls[row * QSTR + col];
    uint4 v1 = *(const uint4*)&Ls[row * QSTR + col + 8];
    half_t* dst;
    if (y == 0)      dst = vtw + ((size_t)bh * 64 + row) * S + s0b + col;
    else {
        half_t* out = (y == 1) ? kw : qw;
        dst = out + ((size_t)bh * S + s0b + row) * 64 + col;
    }
    *(uint4*)dst = v0;
    *(uint4*)(dst + 8) = v1;
}

// ---------------------------------------------------------------------------
// Kernel 2: flash attention, fp16 MFMA, 256 q-rows/block, 512 THREADS
// (8 waves x 32 rows). grid(x=bh, y=qtile): consecutive blocks share q-tile
// -> mask rows hit L2. K/V staged via global_load_lds + XOR gather swizzle,
// double-buffered. p = exp2(st) (Q pre-scaled, shift-free); mask applied as
// one v_and_b32 per packed-P u32 word (prep-expanded fp16 AND-mask), killing
// the per-element bfe/cmp/cndmask chain that made VALUBusy > MfmaUtil.
// l via ones-row MFMA on packed (masked) P - exact bias cancellation.
// ---------------------------------------------------------------------------
__global__ __launch_bounds__(512) void flash_attn_kernel(
    const half_t* __restrict__ q, const half_t* __restrict__ k,
    const half_t* __restrict__ vt, const unsigned short* __restrict__ hm,
    half_t* __restrict__ att)
{
    __shared__ half_t KV[2][2][64 * 64];  // [buf][0=K,1=V][row*8+cp chunks of 8]

    const int tid = threadIdx.x;
    const int w   = tid >> 6;            // 0..7
    const int L   = tid & 63;
    const int a   = L & 15;
    const int g   = L >> 4;
    const int bh  = blockIdx.x;
    const int b_  = bh >> 4, h = bh & 15;
    const int qs  = blockIdx.y * 256 + w * 32;   // wave's 32 q-rows

    const half_t* qb = q  + (size_t)bh * S * 64;
    const half_t* kb = k  + (size_t)bh * S * 64;
    const half_t* vb = vt + (size_t)bh * 64 * S;

    half8v qB[2][2];
    #pragma unroll
    for (int gq = 0; gq < 2; ++gq) {
        const half_t* qr = qb + (size_t)(qs + 16 * gq + a) * 64;
        qB[gq][0] = *(const half8v*)(qr +      g * 8);
        qB[gq][1] = *(const half8v*)(qr + 32 + g * 8);
    }

    // per-lane mask row base: row = q-row, column window starts at 4g
    // (word j covers k positions 16*j+4g .. 16*j+4g+3 of the 64-wide tile)
    const unsigned short* hr[2];
    #pragma unroll
    for (int gq = 0; gq < 2; ++gq)
        hr[gq] = hm + (size_t)(qs + 16 * gq + a) * S + 4 * g;

    // staging: 512 lanes x (1 K-chunk + 1 V-chunk of 8 halves)
    const int p    = w * 64 + L;        // 0..511
    const int srow = p >> 3;
    const int schk = (p & 7) ^ (srow & 7);

    half8v ones;
    #pragma unroll
    for (int i = 0; i < 8; ++i) ones[i] = (half_t)1.0f;

    const float4v z4 = {0.0f, 0.0f, 0.0f, 0.0f};
    float4v o[2][4] = {{z4, z4, z4, z4}, {z4, z4, z4, z4}};
    float4v lD[2] = {z4, z4};

    gl2lds16(kb + (size_t)srow * 64 + schk * 8, &KV[0][0][w * 512]);
    gl2lds16(vb + (size_t)srow * S + schk * 8,  &KV[0][1][w * 512]);

    for (int kt = 0; kt < NTILES; ++kt) {
        const int cur = kt & 1;
        __syncthreads();   // buf[cur] staged (vmcnt drained) + prev reads done

        // mask AND-words for this tile: issued before the staging loads so
        // the compiler's vmcnt wait at first use doesn't drain the gl2lds.
        uint2 mm[2][4];
        #pragma unroll
        for (int gq = 0; gq < 2; ++gq) {
            const unsigned short* hp = hr[gq] + kt * 64;
            #pragma unroll
            for (int j = 0; j < 4; ++j)
                mm[gq][j] = *(const uint2*)(hp + 16 * j);
        }

        if (kt + 1 < NTILES) {
            const int nk = kt + 1;
            gl2lds16(kb + ((size_t)(nk * 64 + srow)) * 64 + schk * 8,
                     &KV[cur ^ 1][0][w * 512]);
            gl2lds16(vb + (size_t)srow * S + nk * 64 + schk * 8,
                     &KV[cur ^ 1][1][w * 512]);
        }

        const half_t* Kb = &KV[cur][0][0];
        const half_t* Vb = &KV[cur][1][0];

        half8v kB[4][2], vA[4][2];
        #pragma unroll
        for (int nt = 0; nt < 4; ++nt)
            #pragma unroll
            for (int c = 0; c < 2; ++c) {
                const int off = ((16 * nt + a) * 8 + ((4 * c + g) ^ (a & 7))) * 8;
                kB[nt][c] = *(const half8v*)(Kb + off);
                vA[nt][c] = *(const half8v*)(Vb + off);
            }

        #pragma unroll
        for (int gq = 0; gq < 2; ++gq) {
            float4v st[4];
            #pragma unroll
            for (int nt = 0; nt < 4; ++nt) {
                st[nt] = __builtin_amdgcn_mfma_f32_16x16x32_f16(kB[nt][0], qB[gq][0], z4, 0, 0, 0);
                st[nt] = __builtin_amdgcn_mfma_f32_16x16x32_f16(kB[nt][1], qB[gq][1], st[nt], 0, 0, 0);
            }

            // exp2 -> pack RTZ -> AND-mask (masked halves become +0.0; inf
            // from masked-overflow exp2 is ANDed away, no 0*inf NaN risk)
            half8v pB[2];
            #pragma unroll
            for (int c = 0; c < 2; ++c) {
                union { unsigned u[4]; half8v hv; } cvt;
                cvt.u[0] = pkh(fast_exp2(st[2*c  ][0]), fast_exp2(st[2*c  ][1])) & mm[gq][2*c  ].x;
                cvt.u[1] = pkh(fast_exp2(st[2*c  ][2]), fast_exp2(st[2*c  ][3])) & mm[gq][2*c  ].y;
                cvt.u[2] = pkh(fast_exp2(st[2*c+1][0]), fast_exp2(st[2*c+1][1])) & mm[gq][2*c+1].x;
                cvt.u[3] = pkh(fast_exp2(st[2*c+1][2]), fast_exp2(st[2*c+1][3])) & mm[gq][2*c+1].y;
                pB[c] = cvt.hv;
            }

            #pragma unroll
            for (int nt = 0; nt < 4; ++nt) {
                o[gq][nt] = __builtin_amdgcn_mfma_f32_16x16x32_f16(vA[nt][0], pB[0], o[gq][nt], 0, 0, 0);
                o[gq][nt] = __builtin_amdgcn_mfma_f32_16x16x32_f16(vA[nt][1], pB[1], o[gq][nt], 0, 0, 0);
            }
            // l per q-row via ones-row MFMA on the SAME packed P
            lD[gq] = __builtin_amdgcn_mfma_f32_16x16x32_f16(ones, pB[0], lD[gq], 0, 0, 0);
            lD[gq] = __builtin_amdgcn_mfma_f32_16x16x32_f16(ones, pB[1], lD[gq], 0, 0, 0);
        }
    }

    #pragma unroll
    for (int gq = 0; gq < 2; ++gq) {
        const float inv = 1.0f / lD[gq][0];   // all 4 components identical
        const size_t row = (size_t)(b_ * S + qs + 16 * gq + a);
        #pragma unroll
        for (int nt = 0; nt < 4; ++nt) {
            union { unsigned u[2]; uint2 u2; } cvt;
            cvt.u[0] = pkh(o[gq][nt][0] * inv, o[gq][nt][1] * inv);
            cvt.u[1] = pkh(o[gq][nt][2] * inv, o[gq][nt][3] * inv);
            *(uint2*)(att + row * DM + h * 64 + 16 * nt + 4 * g) = cvt.u2;
        }
    }
}

// ---------------------------------------------------------------------------
// Kernel 3: output projection, single-term fp16 MFMA GEMM.
// C(8192x1024) = X(fp16) @ Wo(fp16)^T + bo. 128x128 tile, BK=64,
// global_load_lds + XOR gather swizzle, double-buffered (1 barrier/tile).
// ---------------------------------------------------------------------------
__global__ __launch_bounds__(256, 2) void out_proj_kernel(
    const half_t* __restrict__ X, const half_t* __restrict__ Wh,
    const float* __restrict__ bo, float* __restrict__ out)
{
    __shared__ half_t SA[2][128 * 64], SB[2][128 * 64];   // 64 KB total

    const int tid = threadIdx.x;
    const int w = tid >> 6, L = tid & 63, a = L & 15, g = L >> 4;
    const int wm = w >> 1, wn = w & 1;
    const int r0 = blockIdx.x * 128;
    const int n0 = blockIdx.y * 128;

    int prow[4], pchk[4], pbase[4];
    #pragma unroll
    for (int i = 0; i < 4; ++i) {
        int p    = w * 256 + i * 64 + L;
        prow[i]  = p >> 3;
        pchk[i]  = (p & 7) ^ (prow[i] & 7);
        pbase[i] = (w * 256 + i * 64) * 8;   // fp16-element offset of wave base
    }

    const float4v z4 = {0.0f, 0.0f, 0.0f, 0.0f};
    float4v acc[4][4];
    #pragma unroll
    for (int mt = 0; mt < 4; ++mt)
        #pragma unroll
        for (int nt = 0; nt < 4; ++nt) acc[mt][nt] = z4;

    // stage k-tile 0 into buf 0
    #pragma unroll
    for (int i = 0; i < 4; ++i) {
        gl2lds16(X  + (size_t)(r0 + prow[i]) * DM + pchk[i] * 8, &SA[0][pbase[i]]);
        gl2lds16(Wh + (size_t)(n0 + prow[i]) * DM + pchk[i] * 8, &SB[0][pbase[i]]);
    }

    for (int kt = 0; kt < DM / 64; ++kt) {
        const int cur = kt & 1;
        __syncthreads();   // buf[cur] staged + prev frag reads done

        if (kt + 1 < DM / 64) {
            const int k0 = (kt + 1) * 64;
            #pragma unroll
            for (int i = 0; i < 4; ++i) {
                gl2lds16(X  + (size_t)(r0 + prow[i]) * DM + k0 + pchk[i] * 8, &SA[cur ^ 1][pbase[i]]);
                gl2lds16(Wh + (size_t)(n0 + prow[i]) * DM + k0 + pchk[i] * 8, &SB[cur ^ 1][pbase[i]]);
            }
        }

        half8v bF[4][2];
        #pragma unroll
        for (int nt = 0; nt < 4; ++nt)
            #pragma unroll
            for (int c = 0; c < 2; ++c) {
                const int rb  = 64 * wn + 16 * nt + a;
                const int off = (rb * 8 + ((4 * c + g) ^ (rb & 7))) * 8;
                bF[nt][c] = *(const half8v*)&SB[cur][off];
            }

        #pragma unroll
        for (int mt = 0; mt < 4; ++mt) {
            const int ra   = 64 * wm + 16 * mt + a;
            const int off0 = (ra * 8 + ((0 + g) ^ (ra & 7))) * 8;
            const int off1 = (ra * 8 + ((4 + g) ^ (ra & 7))) * 8;
            half8v a0 = *(const half8v*)&SA[cur][off0];
            half8v a1 = *(const half8v*)&SA[cur][off1];
            #pragma unroll
            for (int nt = 0; nt < 4; ++nt) {
                float4v acv = acc[mt][nt];
                acv = __builtin_amdgcn_mfma_f32_16x16x32_f16(a0, bF[nt][0], acv, 0, 0, 0);
                acv = __builtin_amdgcn_mfma_f32_16x16x32_f16(a1, bF[nt][1], acv, 0, 0, 0);
                acc[mt][nt] = acv;
            }
        }
    }

    #pragma unroll
    for (int mt = 0; mt < 4; ++mt) {
        const int m0 = r0 + 64 * wm + 16 * mt + 4 * g;
        #pragma unroll
        for (int nt = 0; nt < 4; ++nt) {
            const int n = n0 + 64 * wn + 16 * nt + a;
            const float bias = bo[n];
            #pragma unroll
            for (int r = 0; r < 4; ++r)
                out[(size_t)(m0 + r) * DM + n] = acc[mt][nt][r] + bias;
        }
    }
}

// ---------------------------------------------------------------------------
extern "C" void kernel_launch(void* const* d_in, const int* in_sizes, int n_in,
                              void* d_out, int out_size, void* d_ws, size_t ws_size,
                              hipStream_t stream) {
    (void)in_sizes; (void)n_in; (void)out_size; (void)ws_size;
    const float* values = (const float*)d_in[0];
    const float* keys   = (const float*)d_in[1];
    const float* query  = (const float*)d_in[2];
    const int*   mask   = (const int*)d_in[3];
    const float* Wv     = (const float*)d_in[4];
    const float* Wk     = (const float*)d_in[5];
    const float* Wq     = (const float*)d_in[6];
    const float* Wo     = (const float*)d_in[7];
    const float* bo     = (const float*)d_in[8];
    float* out = (float*)d_out;

    const size_t per = (size_t)B * H * S * DK;     // 8,388,608 elements
    half_t* qw  = (half_t*)d_ws;
    half_t* kw  = qw + per;
    half_t* vtw = kw + per;
    unsigned short* hm = (unsigned short*)(vtw + per);   // S*S fp16 AND-mask (8 MB)
    half_t* atth = (half_t*)(hm + (size_t)S * S);
    half_t* woh  = atth + per;                     // B*S*DM == per

    prep_kernel<<<HM_BLOCKS + DM * DM / 1024, 256, 0, stream>>>(mask, hm, Wo, woh);

    dim3 g1(B * H * (S / 64), 3);
    qkv_proj_kernel<<<g1, 256, 0, stream>>>(values, keys, query, Wv, Wk, Wq, vtw, kw, qw);

    dim3 g2(B * H, S / 256);   // x=bh -> consecutive blocks share q-tile mask rows (L2)
    flash_attn_kernel<<<g2, 512, 0, stream>>>(qw, kw, vtw, hm, atth);

    dim3 g3(B * S / 128, DM / 128);
    out_proj_kernel<<<g3, 256, 0, stream>>>(atth, woh, bo, out);
}

// Round 3
// 330.089 us; speedup vs baseline: 1.1335x; 1.1335x over previous
//
#include <hip/hip_runtime.h>

#define B 4
#define S 2048
#define H 16
#define DK 64
#define DM 1024
#define NTILES (S / 64)
#define QSCALE 0.18033688011112042f   // 0.125 * log2(e); folded into Q projection

typedef _Float16 half_t;
typedef __attribute__((ext_vector_type(8))) _Float16 half8v;   // 8 fp16 = MFMA A/B frag
typedef __attribute__((ext_vector_type(2))) __fp16   fp16x2;   // builtin return type
typedef __attribute__((ext_vector_type(4))) float    float4v;  // MFMA C/D frag

// pack two fp32 -> fp16x2 RTZ in one v_cvt_pkrtz (bias cancels in softmax O/l)
__device__ __forceinline__ unsigned pkh(float lo, float hi) {
    union { fp16x2 h; unsigned u; } cvt;
    cvt.h = __builtin_amdgcn_cvt_pkrtz(lo, hi);
    return cvt.u;
}
__device__ __forceinline__ float fast_exp2(float x) {
#if __has_builtin(__builtin_amdgcn_exp2f)
    return __builtin_amdgcn_exp2f(x);
#else
    return __expf(x * 0.69314718055994531f);
#endif
}
// convert 8 fp32 (two float4, consecutive k) -> fp16 frag (RNE v_cvt_f16_f32)
__device__ __forceinline__ half8v cvt8h(float4 a, float4 b) {
    half8v r;
    r[0] = (half_t)a.x; r[1] = (half_t)a.y; r[2] = (half_t)a.z; r[3] = (half_t)a.w;
    r[4] = (half_t)b.x; r[5] = (half_t)b.y; r[6] = (half_t)b.z; r[7] = (half_t)b.w;
    return r;
}
// async global -> LDS. LDS dest = wave-uniform base + lane*size; global src per-lane.
__device__ __forceinline__ void gl2lds16(const void* g, void* l) {
    __builtin_amdgcn_global_load_lds(
        (const __attribute__((address_space(1))) unsigned int*)g,
        (__attribute__((address_space(3))) unsigned int*)l, 16, 0, 0);
}
__device__ __forceinline__ void gl2lds4(const void* g, void* l) {
    __builtin_amdgcn_global_load_lds(
        (const __attribute__((address_space(1))) unsigned int*)g,
        (__attribute__((address_space(3))) unsigned int*)l, 4, 0, 0);
}

// ---------------------------------------------------------------------------
// Kernel 0: fused prep. Blocks [0, S*S/256): pack mask bits, TRANSPOSED
// layout mpT[kt * S + row] so a block's 256 rows for one k-tile are 2 KB
// contiguous (stageable via global_load_lds). Blocks [+, +DM*DM/1024): Wo->fp16.
// ---------------------------------------------------------------------------
#define MASK_BLOCKS (S * S / 256)
__global__ __launch_bounds__(256) void prep_kernel(
    const int* __restrict__ mask, unsigned long long* __restrict__ mpT,
    const float* __restrict__ Wo, half_t* __restrict__ Wh)
{
    int bx = blockIdx.x;
    if (bx < MASK_BLOCKS) {
        int t = bx * 256 + threadIdx.x;
        int m = mask[t];
        unsigned long long b = __ballot(m != 0);
        if ((threadIdx.x & 63) == 0) {
            int row = t >> 11;            // t / S
            int kt  = (t & (S - 1)) >> 6; // (t % S) / 64
            mpT[(size_t)kt * S + row] = b;
        }
    } else {
        int t = ((bx - MASK_BLOCKS) * 256 + threadIdx.x) * 4;
        float4 wv = *(const float4*)(Wo + t);
        union { half_t h[4]; uint2 u; } cvt;
        cvt.h[0] = (half_t)wv.x; cvt.h[1] = (half_t)wv.y;
        cvt.h[2] = (half_t)wv.z; cvt.h[3] = (half_t)wv.w;
        *(uint2*)(Wh + t) = cvt.u;
    }
}

// ---------------------------------------------------------------------------
// Kernel 1: QKV projection via fp16 MFMA. Output bounced through padded LDS
// tile (stride 72: 16B-aligned rows, bank-spread) -> two 16B global stores
// per lane instead of 16 scalar 2B stores.
// y=0: V -> Vt (B,H,64,S) with PV-permuted columns; y=1: K; y=2: Q (scaled).
// ---------------------------------------------------------------------------
#define QSTR 72   // LDS bounce-tile stride (halves): 144B rows, 16B aligned
__global__ __launch_bounds__(256) void qkv_proj_kernel(
    const float* __restrict__ xv, const float* __restrict__ xk, const float* __restrict__ xq,
    const float* __restrict__ Wv, const float* __restrict__ Wk, const float* __restrict__ Wq,
    half_t* __restrict__ vtw, half_t* __restrict__ kw, half_t* __restrict__ qw)
{
    __shared__ half_t Ls[64 * QSTR];

    const int y = blockIdx.y;
    const float* x; const float* W;
    if (y == 0)      { x = xv; W = Wv; }
    else if (y == 1) { x = xk; W = Wk; }
    else             { x = xq; W = Wq; }

    const int tid = threadIdx.x;
    const int w = tid >> 6, L = tid & 63, a = L & 15, g = L >> 4;
    const int bx  = blockIdx.x;
    const int st  = bx & 31;
    const int bh  = bx >> 5;
    const int b_  = bh >> 4, h = bh & 15;
    const int s0b = st * 64;

    // W fragments: lane a <-> dim-row 16t+a, quad g <-> k-chunk
    half8v wF[4][2];
    #pragma unroll
    for (int t = 0; t < 4; ++t)
        #pragma unroll
        for (int c = 0; c < 2; ++c) {
            const float* wr = W + (size_t)(16 * t + a) * 64 + 32 * c + 8 * g;
            wF[t][c] = cvt8h(*(const float4*)wr, *(const float4*)(wr + 4));
        }

    // x fragments: lane a <-> s-row s0b+16w+a
    const float* xr = x + ((size_t)(b_ * S) + s0b + 16 * w + a) * DM + h * 64 + 8 * g;
    half8v xF0 = cvt8h(*(const float4*)(xr),      *(const float4*)(xr + 4));
    half8v xF1 = cvt8h(*(const float4*)(xr + 32), *(const float4*)(xr + 36));

    const float4v z4 = {0.0f, 0.0f, 0.0f, 0.0f};

    if (y == 0) {
        // V^T: A = W (m=d), B = x (n=s). D[m=4g+r][n=a]. Ls[d][pos]
        const int c   = 16 * w + a;
        const int pos = 32 * (c >> 5) + 8 * ((c >> 2) & 3) + 4 * ((c >> 4) & 1) + (c & 3);
        #pragma unroll
        for (int mt = 0; mt < 4; ++mt) {
            float4v D = __builtin_amdgcn_mfma_f32_16x16x32_f16(wF[mt][0], xF0, z4, 0, 0, 0);
            D = __builtin_amdgcn_mfma_f32_16x16x32_f16(wF[mt][1], xF1, D, 0, 0, 0);
            #pragma unroll
            for (int r = 0; r < 4; ++r)
                Ls[(16 * mt + 4 * g + r) * QSTR + pos] = (half_t)D[r];
        }
    } else {
        const float scale = (y == 2) ? QSCALE : 1.0f;
        #pragma unroll
        for (int nt = 0; nt < 4; ++nt) {
            float4v D = __builtin_amdgcn_mfma_f32_16x16x32_f16(xF0, wF[nt][0], z4, 0, 0, 0);
            D = __builtin_amdgcn_mfma_f32_16x16x32_f16(xF1, wF[nt][1], D, 0, 0, 0);
            #pragma unroll
            for (int r = 0; r < 4; ++r)
                Ls[(16 * w + 4 * g + r) * QSTR + 16 * nt + a] = (half_t)(D[r] * scale);
        }
    }
    __syncthreads();

    // coalesced copy-out: each thread 16 halves (two 16B stores), 4 threads/row
    const int row = tid >> 2;
    const int col = (tid & 3) * 16;
    uint4 v0 = *(const uint4*)&Ls[row * QSTR + col];
    uint4 v1 = *(const uint4*)&Ls[row * QSTR + col + 8];
    half_t* dst;
    if (y == 0)      dst = vtw + ((size_t)bh * 64 + row) * S + s0b + col;
    else {
        half_t* out = (y == 1) ? kw : qw;
        dst = out + ((size_t)bh * S + s0b + row) * 64 + col;
    }
    *(uint4*)dst = v0;
    *(uint4*)(dst + 8) = v1;
}

// ---------------------------------------------------------------------------
// Kernel 2: flash attention, fp16 MFMA, 256 q-rows/block, 512 THREADS
// (8 waves x 32 rows). Pipelined: 4 LDS buffers, K/V/mask all staged 2 TILES
// AHEAD via global_load_lds -- the vmcnt stream is PURE LDS-DMA (3 ops/tile),
// matching the verified counted-vmcnt template. Raw s_barrier + s_waitcnt
// vmcnt(3) (vmcnt(0) only on the last tile): loads stay in flight across
// barriers. Q-frag loads drained once before the prologue so no ordinary
// VMEM pollutes the count. Masks read from LDS after the same barrier.
// Compute numerics identical to the verified round-0 kernel.
// ---------------------------------------------------------------------------
__global__ __launch_bounds__(512) void flash_attn_kernel(
    const half_t* __restrict__ q, const half_t* __restrict__ k,
    const half_t* __restrict__ vt, const unsigned long long* __restrict__ mpT,
    half_t* __restrict__ att)
{
    __shared__ half_t KV[4][2][64 * 64];          // 64 KB: [buf][0=K,1=V]
    __shared__ unsigned long long Ms[4][256];     // 8 KB: [buf][block q-row]

    const int tid = threadIdx.x;
    const int w   = tid >> 6;            // 0..7
    const int L   = tid & 63;
    const int a   = L & 15;
    const int g   = L >> 4;
    const int bh  = blockIdx.x;
    const int b_  = bh >> 4, h = bh & 15;
    const int qs0 = blockIdx.y * 256;
    const int qs  = qs0 + w * 32;        // wave's 32 q-rows

    const half_t* qb = q  + (size_t)bh * S * 64;
    const half_t* kb = k  + (size_t)bh * S * 64;
    const half_t* vb = vt + (size_t)bh * 64 * S;
    const unsigned long long* mq = mpT + qs0;     // + kt*S, rows contiguous

    half8v qB[2][2];
    #pragma unroll
    for (int gq = 0; gq < 2; ++gq) {
        const half_t* qr = qb + (size_t)(qs + 16 * gq + a) * 64;
        qB[gq][0] = *(const half8v*)(qr +      g * 8);
        qB[gq][1] = *(const half8v*)(qr + 32 + g * 8);
    }
    // drain Q loads: vmcnt stream must contain ONLY LDS-DMA from here on
    asm volatile("s_waitcnt vmcnt(0)" ::: "memory");
    __builtin_amdgcn_sched_barrier(0);

    // staging: 512 lanes x (K-chunk 16B + V-chunk 16B + mask word 4B)
    const int p    = w * 64 + L;        // 0..511
    const int srow = p >> 3;
    const int schk = (p & 7) ^ (srow & 7);
    const size_t kgo = (size_t)srow * 64 + schk * 8;  // + kt*4096
    const size_t vgo = (size_t)srow * S  + schk * 8;  // + kt*64

    half8v ones;
    #pragma unroll
    for (int i = 0; i < 8; ++i) ones[i] = (half_t)1.0f;

    const float4v z4 = {0.0f, 0.0f, 0.0f, 0.0f};
    float4v o[2][4] = {{z4, z4, z4, z4}, {z4, z4, z4, z4}};
    float4v lD[2] = {z4, z4};

    // stage tile kt2 into buffer nb: exactly 3 LDS-DMA ops per lane
    auto stage = [&](int kt2, int nb) {
        gl2lds16(kb + (size_t)kt2 * 4096 + kgo, &KV[nb][0][w * 512]);
        gl2lds16(vb + (size_t)kt2 * 64   + vgo, &KV[nb][1][w * 512]);
        gl2lds4((const unsigned int*)(mq + (size_t)kt2 * S) + p, &Ms[nb][w * 32]);
    };

    auto compute = [&](int cur) {
        const half_t* Kb = &KV[cur][0][0];
        const half_t* Vb = &KV[cur][1][0];

        unsigned long long mw[2];
        mw[0] = Ms[cur][w * 32 +      a];
        mw[1] = Ms[cur][w * 32 + 16 + a];

        half8v kB[4][2], vA[4][2];
        #pragma unroll
        for (int nt = 0; nt < 4; ++nt)
            #pragma unroll
            for (int c = 0; c < 2; ++c) {
                const int off = ((16 * nt + a) * 8 + ((4 * c + g) ^ (a & 7))) * 8;
                kB[nt][c] = *(const half8v*)(Kb + off);
                vA[nt][c] = *(const half8v*)(Vb + off);
            }

        #pragma unroll
        for (int gq = 0; gq < 2; ++gq) {
            float4v st[4];
            __builtin_amdgcn_s_setprio(1);
            #pragma unroll
            for (int nt = 0; nt < 4; ++nt) {
                st[nt] = __builtin_amdgcn_mfma_f32_16x16x32_f16(kB[nt][0], qB[gq][0], z4, 0, 0, 0);
                st[nt] = __builtin_amdgcn_mfma_f32_16x16x32_f16(kB[nt][1], qB[gq][1], st[nt], 0, 0, 0);
            }
            __builtin_amdgcn_s_setprio(0);

            float e[4][4];
            #pragma unroll
            for (int nt = 0; nt < 4; ++nt) {
                unsigned bnt = (unsigned)(mw[gq] >> (16 * nt + 4 * g));
                #pragma unroll
                for (int r = 0; r < 4; ++r) {
                    float ee = fast_exp2(st[nt][r]);       // single v_exp_f32
                    e[nt][r] = ((bnt >> r) & 1u) ? ee : 0.0f;
                }
            }

            half8v pB[2];
            #pragma unroll
            for (int c = 0; c < 2; ++c) {
                union { unsigned u[4]; half8v hv; } cvt;
                cvt.u[0] = pkh(e[2*c  ][0], e[2*c  ][1]);
                cvt.u[1] = pkh(e[2*c  ][2], e[2*c  ][3]);
                cvt.u[2] = pkh(e[2*c+1][0], e[2*c+1][1]);
                cvt.u[3] = pkh(e[2*c+1][2], e[2*c+1][3]);
                pB[c] = cvt.hv;
            }

            __builtin_amdgcn_s_setprio(1);
            #pragma unroll
            for (int nt = 0; nt < 4; ++nt) {
                o[gq][nt] = __builtin_amdgcn_mfma_f32_16x16x32_f16(vA[nt][0], pB[0], o[gq][nt], 0, 0, 0);
                o[gq][nt] = __builtin_amdgcn_mfma_f32_16x16x32_f16(vA[nt][1], pB[1], o[gq][nt], 0, 0, 0);
            }
            // l per q-row via ones-row MFMA on the SAME packed P
            lD[gq] = __builtin_amdgcn_mfma_f32_16x16x32_f16(ones, pB[0], lD[gq], 0, 0, 0);
            lD[gq] = __builtin_amdgcn_mfma_f32_16x16x32_f16(ones, pB[1], lD[gq], 0, 0, 0);
            __builtin_amdgcn_s_setprio(0);
        }
    };

    // prologue: stage tiles 0,1 -> 6 LDS-DMA outstanding
    stage(0, 0);
    stage(1, 1);
    __builtin_amdgcn_sched_barrier(0);

    for (int kt = 0; kt < NTILES; ++kt) {
        const int cur = kt & 3;
        __builtin_amdgcn_sched_barrier(0);
        // outstanding (oldest first): glds kt (3), glds kt+1 (3 if staged).
        // vmcnt(3) retires exactly tile kt's staging trio.
        if (kt < NTILES - 1) asm volatile("s_waitcnt vmcnt(3)" ::: "memory");
        else                 asm volatile("s_waitcnt vmcnt(0)" ::: "memory");
        __builtin_amdgcn_s_barrier();
        __builtin_amdgcn_sched_barrier(0);
        if (kt + 2 < NTILES) {
            stage(kt + 2, (kt + 2) & 3);
            __builtin_amdgcn_sched_barrier(0);
        }
        compute(cur);
    }

    #pragma unroll
    for (int gq = 0; gq < 2; ++gq) {
        const float inv = 1.0f / lD[gq][0];   // all 4 components identical
        const size_t row = (size_t)(b_ * S + qs + 16 * gq + a);
        #pragma unroll
        for (int nt = 0; nt < 4; ++nt) {
            union { unsigned u[2]; uint2 u2; } cvt;
            cvt.u[0] = pkh(o[gq][nt][0] * inv, o[gq][nt][1] * inv);
            cvt.u[1] = pkh(o[gq][nt][2] * inv, o[gq][nt][3] * inv);
            *(uint2*)(att + row * DM + h * 64 + 16 * nt + 4 * g) = cvt.u2;
        }
    }
}

// ---------------------------------------------------------------------------
// Kernel 3: output projection, single-term fp16 MFMA GEMM.
// C(8192x1024) = X(fp16) @ Wo(fp16)^T + bo. 128x128 tile, BK=64,
// global_load_lds + XOR gather swizzle, double-buffered (1 barrier/tile).
// ---------------------------------------------------------------------------
__global__ __launch_bounds__(256, 2) void out_proj_kernel(
    const half_t* __restrict__ X, const half_t* __restrict__ Wh,
    const float* __restrict__ bo, float* __restrict__ out)
{
    __shared__ half_t SA[2][128 * 64], SB[2][128 * 64];   // 64 KB total

    const int tid = threadIdx.x;
    const int w = tid >> 6, L = tid & 63, a = L & 15, g = L >> 4;
    const int wm = w >> 1, wn = w & 1;
    const int r0 = blockIdx.x * 128;
    const int n0 = blockIdx.y * 128;

    int prow[4], pchk[4], pbase[4];
    #pragma unroll
    for (int i = 0; i < 4; ++i) {
        int p    = w * 256 + i * 64 + L;
        prow[i]  = p >> 3;
        pchk[i]  = (p & 7) ^ (prow[i] & 7);
        pbase[i] = (w * 256 + i * 64) * 8;   // fp16-element offset of wave base
    }

    const float4v z4 = {0.0f, 0.0f, 0.0f, 0.0f};
    float4v acc[4][4];
    #pragma unroll
    for (int mt = 0; mt < 4; ++mt)
        #pragma unroll
        for (int nt = 0; nt < 4; ++nt) acc[mt][nt] = z4;

    // stage k-tile 0 into buf 0
    #pragma unroll
    for (int i = 0; i < 4; ++i) {
        gl2lds16(X  + (size_t)(r0 + prow[i]) * DM + pchk[i] * 8, &SA[0][pbase[i]]);
        gl2lds16(Wh + (size_t)(n0 + prow[i]) * DM + pchk[i] * 8, &SB[0][pbase[i]]);
    }

    for (int kt = 0; kt < DM / 64; ++kt) {
        const int cur = kt & 1;
        __syncthreads();   // buf[cur] staged + prev frag reads done

        if (kt + 1 < DM / 64) {
            const int k0 = (kt + 1) * 64;
            #pragma unroll
            for (int i = 0; i < 4; ++i) {
                gl2lds16(X  + (size_t)(r0 + prow[i]) * DM + k0 + pchk[i] * 8, &SA[cur ^ 1][pbase[i]]);
                gl2lds16(Wh + (size_t)(n0 + prow[i]) * DM + k0 + pchk[i] * 8, &SB[cur ^ 1][pbase[i]]);
            }
        }

        half8v bF[4][2];
        #pragma unroll
        for (int nt = 0; nt < 4; ++nt)
            #pragma unroll
            for (int c = 0; c < 2; ++c) {
                const int rb  = 64 * wn + 16 * nt + a;
                const int off = (rb * 8 + ((4 * c + g) ^ (rb & 7))) * 8;
                bF[nt][c] = *(const half8v*)&SB[cur][off];
            }

        #pragma unroll
        for (int mt = 0; mt < 4; ++mt) {
            const int ra   = 64 * wm + 16 * mt + a;
            const int off0 = (ra * 8 + ((0 + g) ^ (ra & 7))) * 8;
            const int off1 = (ra * 8 + ((4 + g) ^ (ra & 7))) * 8;
            half8v a0 = *(const half8v*)&SA[cur][off0];
            half8v a1 = *(const half8v*)&SA[cur][off1];
            #pragma unroll
            for (int nt = 0; nt < 4; ++nt) {
                float4v acv = acc[mt][nt];
                acv = __builtin_amdgcn_mfma_f32_16x16x32_f16(a0, bF[nt][0], acv, 0, 0, 0);
                acv = __builtin_amdgcn_mfma_f32_16x16x32_f16(a1, bF[nt][1], acv, 0, 0, 0);
                acc[mt][nt] = acv;
            }
        }
    }

    #pragma unroll
    for (int mt = 0; mt < 4; ++mt) {
        const int m0 = r0 + 64 * wm + 16 * mt + 4 * g;
        #pragma unroll
        for (int nt = 0; nt < 4; ++nt) {
            const int n = n0 + 64 * wn + 16 * nt + a;
            const float bias = bo[n];
            #pragma unroll
            for (int r = 0; r < 4; ++r)
                out[(size_t)(m0 + r) * DM + n] = acc[mt][nt][r] + bias;
        }
    }
}

// ---------------------------------------------------------------------------
extern "C" void kernel_launch(void* const* d_in, const int* in_sizes, int n_in,
                              void* d_out, int out_size, void* d_ws, size_t ws_size,
                              hipStream_t stream) {
    (void)in_sizes; (void)n_in; (void)out_size; (void)ws_size;
    const float* values = (const float*)d_in[0];
    const float* keys   = (const float*)d_in[1];
    const float* query  = (const float*)d_in[2];
    const int*   mask   = (const int*)d_in[3];
    const float* Wv     = (const float*)d_in[4];
    const float* Wk     = (const float*)d_in[5];
    const float* Wq     = (const float*)d_in[6];
    const float* Wo     = (const float*)d_in[7];
    const float* bo     = (const float*)d_in[8];
    float* out = (float*)d_out;

    const size_t per = (size_t)B * H * S * DK;     // 8,388,608 elements
    half_t* qw  = (half_t*)d_ws;
    half_t* kw  = qw + per;
    half_t* vtw = kw + per;
    unsigned long long* mpT = (unsigned long long*)(vtw + per);  // [kt][row]
    half_t* atth = (half_t*)(mpT + (size_t)S * S / 64);
    half_t* woh  = atth + per;                     // B*S*DM == per

    prep_kernel<<<MASK_BLOCKS + DM * DM / 1024, 256, 0, stream>>>(mask, mpT, Wo, woh);

    dim3 g1(B * H * (S / 64), 3);
    qkv_proj_kernel<<<g1, 256, 0, stream>>>(values, keys, query, Wv, Wk, Wq, vtw, kw, qw);

    dim3 g2(B * H, S / 256);   // x=bh -> blockId%8 = head%8 (XCD L2 locality)
    flash_attn_kernel<<<g2, 512, 0, stream>>>(qw, kw, vtw, mpT, atth);

    dim3 g3(B * S / 128, DM / 128);
    out_proj_kernel<<<g3, 256, 0, stream>>>(atth, woh, bo, out);
}

// Round 4
// 325.161 us; speedup vs baseline: 1.1507x; 1.0152x over previous
//
#include <hip/hip_runtime.h>

#define B 4
#define S 2048
#define H 16
#define DK 64
#define DM 1024
#define NTILES (S / 64)
#define NPHASES (NTILES / 2)
#define QSCALE 0.18033688011112042f   // 0.125 * log2(e); folded into Q projection

typedef _Float16 half_t;
typedef __attribute__((ext_vector_type(8))) _Float16 half8v;   // 8 fp16 = MFMA A/B frag
typedef __attribute__((ext_vector_type(2))) __fp16   fp16x2;   // builtin return type
typedef __attribute__((ext_vector_type(4))) float    float4v;  // MFMA C/D frag

// pack two fp32 -> fp16x2 RTZ in one v_cvt_pkrtz (bias cancels in softmax O/l)
__device__ __forceinline__ unsigned pkh(float lo, float hi) {
    union { fp16x2 h; unsigned u; } cvt;
    cvt.h = __builtin_amdgcn_cvt_pkrtz(lo, hi);
    return cvt.u;
}
__device__ __forceinline__ float fast_exp2(float x) {
#if __has_builtin(__builtin_amdgcn_exp2f)
    return __builtin_amdgcn_exp2f(x);
#else
    return __expf(x * 0.69314718055994531f);
#endif
}
// convert 8 fp32 (two float4, consecutive k) -> fp16 frag (RNE v_cvt_f16_f32)
__device__ __forceinline__ half8v cvt8h(float4 a, float4 b) {
    half8v r;
    r[0] = (half_t)a.x; r[1] = (half_t)a.y; r[2] = (half_t)a.z; r[3] = (half_t)a.w;
    r[4] = (half_t)b.x; r[5] = (half_t)b.y; r[6] = (half_t)b.z; r[7] = (half_t)b.w;
    return r;
}
// async global -> LDS, 16B per lane. LDS dest = wave-uniform base + lane*16.
__device__ __forceinline__ void gl2lds16(const void* g, void* l) {
    __builtin_amdgcn_global_load_lds(
        (const __attribute__((address_space(1))) unsigned int*)g,
        (__attribute__((address_space(3))) unsigned int*)l, 16, 0, 0);
}

// ---------------------------------------------------------------------------
// Kernel 0: fused prep. Blocks [0, S*S/256): pack mask bits.
// Blocks [S*S/256, +DM*DM/1024): convert Wo fp32 -> fp16.
// ---------------------------------------------------------------------------
#define MASK_BLOCKS (S * S / 256)
__global__ __launch_bounds__(256) void prep_kernel(
    const int* __restrict__ mask, unsigned long long* __restrict__ mp,
    const float* __restrict__ Wo, half_t* __restrict__ Wh)
{
    int bx = blockIdx.x;
    if (bx < MASK_BLOCKS) {
        int t = bx * 256 + threadIdx.x;
        int m = mask[t];
        unsigned long long b = __ballot(m != 0);
        if ((threadIdx.x & 63) == 0) mp[t >> 6] = b;
    } else {
        int t = ((bx - MASK_BLOCKS) * 256 + threadIdx.x) * 4;
        float4 wv = *(const float4*)(Wo + t);
        union { half_t h[4]; uint2 u; } cvt;
        cvt.h[0] = (half_t)wv.x; cvt.h[1] = (half_t)wv.y;
        cvt.h[2] = (half_t)wv.z; cvt.h[3] = (half_t)wv.w;
        *(uint2*)(Wh + t) = cvt.u;
    }
}

// ---------------------------------------------------------------------------
// Kernel 1: QKV projection via fp16 MFMA. Output bounced through padded LDS
// tile (stride 72: 16B-aligned rows, bank-spread) -> two 16B global stores
// per lane instead of 16 scalar 2B stores.
// y=0: V -> Vt (B,H,64,S) with PV-permuted columns; y=1: K; y=2: Q (scaled).
// ---------------------------------------------------------------------------
#define QSTR 72   // LDS bounce-tile stride (halves): 144B rows, 16B aligned
__global__ __launch_bounds__(256) void qkv_proj_kernel(
    const float* __restrict__ xv, const float* __restrict__ xk, const float* __restrict__ xq,
    const float* __restrict__ Wv, const float* __restrict__ Wk, const float* __restrict__ Wq,
    half_t* __restrict__ vtw, half_t* __restrict__ kw, half_t* __restrict__ qw)
{
    __shared__ half_t Ls[64 * QSTR];

    const int y = blockIdx.y;
    const float* x; const float* W;
    if (y == 0)      { x = xv; W = Wv; }
    else if (y == 1) { x = xk; W = Wk; }
    else             { x = xq; W = Wq; }

    const int tid = threadIdx.x;
    const int w = tid >> 6, L = tid & 63, a = L & 15, g = L >> 4;
    const int bx  = blockIdx.x;
    const int st  = bx & 31;
    const int bh  = bx >> 5;
    const int b_  = bh >> 4, h = bh & 15;
    const int s0b = st * 64;

    // W fragments: lane a <-> dim-row 16t+a, quad g <-> k-chunk
    half8v wF[4][2];
    #pragma unroll
    for (int t = 0; t < 4; ++t)
        #pragma unroll
        for (int c = 0; c < 2; ++c) {
            const float* wr = W + (size_t)(16 * t + a) * 64 + 32 * c + 8 * g;
            wF[t][c] = cvt8h(*(const float4*)wr, *(const float4*)(wr + 4));
        }

    // x fragments: lane a <-> s-row s0b+16w+a
    const float* xr = x + ((size_t)(b_ * S) + s0b + 16 * w + a) * DM + h * 64 + 8 * g;
    half8v xF0 = cvt8h(*(const float4*)(xr),      *(const float4*)(xr + 4));
    half8v xF1 = cvt8h(*(const float4*)(xr + 32), *(const float4*)(xr + 36));

    const float4v z4 = {0.0f, 0.0f, 0.0f, 0.0f};

    if (y == 0) {
        // V^T: A = W (m=d), B = x (n=s). D[m=4g+r][n=a]. Ls[d][pos]
        const int c   = 16 * w + a;
        const int pos = 32 * (c >> 5) + 8 * ((c >> 2) & 3) + 4 * ((c >> 4) & 1) + (c & 3);
        #pragma unroll
        for (int mt = 0; mt < 4; ++mt) {
            float4v D = __builtin_amdgcn_mfma_f32_16x16x32_f16(wF[mt][0], xF0, z4, 0, 0, 0);
            D = __builtin_amdgcn_mfma_f32_16x16x32_f16(wF[mt][1], xF1, D, 0, 0, 0);
            #pragma unroll
            for (int r = 0; r < 4; ++r)
                Ls[(16 * mt + 4 * g + r) * QSTR + pos] = (half_t)D[r];
        }
    } else {
        const float scale = (y == 2) ? QSCALE : 1.0f;
        #pragma unroll
        for (int nt = 0; nt < 4; ++nt) {
            float4v D = __builtin_amdgcn_mfma_f32_16x16x32_f16(xF0, wF[nt][0], z4, 0, 0, 0);
            D = __builtin_amdgcn_mfma_f32_16x16x32_f16(xF1, wF[nt][1], D, 0, 0, 0);
            #pragma unroll
            for (int r = 0; r < 4; ++r)
                Ls[(16 * w + 4 * g + r) * QSTR + 16 * nt + a] = (half_t)(D[r] * scale);
        }
    }
    __syncthreads();

    // coalesced copy-out: each thread 16 halves (two 16B stores), 4 threads/row
    const int row = tid >> 2;
    const int col = (tid & 3) * 16;
    uint4 v0 = *(const uint4*)&Ls[row * QSTR + col];
    uint4 v1 = *(const uint4*)&Ls[row * QSTR + col + 8];
    half_t* dst;
    if (y == 0)      dst = vtw + ((size_t)bh * 64 + row) * S + s0b + col;
    else {
        half_t* out = (y == 1) ? kw : qw;
        dst = out + ((size_t)bh * S + s0b + row) * 64 + col;
    }
    *(uint4*)dst = v0;
    *(uint4*)(dst + 8) = v1;
}

// ---------------------------------------------------------------------------
// Kernel 2: flash attention, fp16 MFMA, 256 q-rows/block, 512 THREADS
// (8 waves x 32 rows). Round-0 verified sync structure (double-buffered
// __syncthreads, stage-after-barrier, register mask loads) but BK=128:
// TWO 64-row K/V tiles staged/computed per barrier phase -> 16 barriers
// instead of 32, and two independent sub-tile dependency chains per phase
// for the scheduler to overlap. Numerics bit-identical to round 0.
// ---------------------------------------------------------------------------
__global__ __launch_bounds__(512) void flash_attn_kernel(
    const half_t* __restrict__ q, const half_t* __restrict__ k,
    const half_t* __restrict__ vt, const unsigned long long* __restrict__ mp,
    half_t* __restrict__ att)
{
    __shared__ half_t KV[2][2][128 * 64];  // [buf][0=K,1=V][row*64+...] = 64 KB

    const int tid = threadIdx.x;
    const int w   = tid >> 6;            // 0..7
    const int L   = tid & 63;
    const int a   = L & 15;
    const int g   = L >> 4;
    const int bh  = blockIdx.x;
    const int b_  = bh >> 4, h = bh & 15;
    const int qs  = blockIdx.y * 256 + w * 32;   // wave's 32 q-rows

    const half_t* qb = q  + (size_t)bh * S * 64;
    const half_t* kb = k  + (size_t)bh * S * 64;
    const half_t* vb = vt + (size_t)bh * 64 * S;

    half8v qB[2][2];
    #pragma unroll
    for (int gq = 0; gq < 2; ++gq) {
        const half_t* qr = qb + (size_t)(qs + 16 * gq + a) * 64;
        qB[gq][0] = *(const half8v*)(qr +      g * 8);
        qB[gq][1] = *(const half8v*)(qr + 32 + g * 8);
    }

    const unsigned long long* mr[2];
    #pragma unroll
    for (int gq = 0; gq < 2; ++gq)
        mr[gq] = mp + (size_t)(qs + 16 * gq + a) * NTILES;

    // staging: 512 lanes; per 64-row sub-tile each lane moves 1 K-chunk +
    // 1 V-chunk of 8 halves (16B). srow in [0,64), XOR-swizzled chunk.
    const int p    = w * 64 + L;        // 0..511
    const int srow = p >> 3;
    const int schk = (p & 7) ^ (srow & 7);
    const size_t kgo = (size_t)srow * 64 + schk * 8;
    const size_t vgo = (size_t)srow * S  + schk * 8;

    half8v ones;
    #pragma unroll
    for (int i = 0; i < 8; ++i) ones[i] = (half_t)1.0f;

    const float4v z4 = {0.0f, 0.0f, 0.0f, 0.0f};
    float4v o[2][4] = {{z4, z4, z4, z4}, {z4, z4, z4, z4}};
    float4v lD[2] = {z4, z4};

    // stage phase ph (two 64-row tiles: rows ph*128 .. ph*128+127) into buf
    auto stage = [&](int ph, int buf) {
        const size_t kr = (size_t)ph * 128 * 64;   // element offset of row ph*128
        const size_t vc = (size_t)ph * 128;        // column offset
        gl2lds16(kb + kr        + kgo, &KV[buf][0][       w * 512]);
        gl2lds16(kb + kr + 4096 + kgo, &KV[buf][0][4096 + w * 512]);
        gl2lds16(vb + vc        + vgo, &KV[buf][1][       w * 512]);
        gl2lds16(vb + vc + 64   + vgo, &KV[buf][1][4096 + w * 512]);
    };

    // compute one 64-row sub-tile from LDS (round-0 body, verified)
    auto compute = [&](const half_t* Kb, const half_t* Vb,
                       unsigned long long mw0, unsigned long long mw1) {
        half8v kB[4][2], vA[4][2];
        #pragma unroll
        for (int nt = 0; nt < 4; ++nt)
            #pragma unroll
            for (int c = 0; c < 2; ++c) {
                const int off = ((16 * nt + a) * 8 + ((4 * c + g) ^ (a & 7))) * 8;
                kB[nt][c] = *(const half8v*)(Kb + off);
                vA[nt][c] = *(const half8v*)(Vb + off);
            }

        const unsigned long long mw[2] = { mw0, mw1 };
        #pragma unroll
        for (int gq = 0; gq < 2; ++gq) {
            float4v st[4];
            #pragma unroll
            for (int nt = 0; nt < 4; ++nt) {
                st[nt] = __builtin_amdgcn_mfma_f32_16x16x32_f16(kB[nt][0], qB[gq][0], z4, 0, 0, 0);
                st[nt] = __builtin_amdgcn_mfma_f32_16x16x32_f16(kB[nt][1], qB[gq][1], st[nt], 0, 0, 0);
            }

            float e[4][4];
            #pragma unroll
            for (int nt = 0; nt < 4; ++nt) {
                unsigned bnt = (unsigned)(mw[gq] >> (16 * nt + 4 * g));
                #pragma unroll
                for (int r = 0; r < 4; ++r) {
                    float ee = fast_exp2(st[nt][r]);       // single v_exp_f32
                    e[nt][r] = ((bnt >> r) & 1u) ? ee : 0.0f;
                }
            }

            half8v pB[2];
            #pragma unroll
            for (int c = 0; c < 2; ++c) {
                union { unsigned u[4]; half8v hv; } cvt;
                cvt.u[0] = pkh(e[2*c  ][0], e[2*c  ][1]);
                cvt.u[1] = pkh(e[2*c  ][2], e[2*c  ][3]);
                cvt.u[2] = pkh(e[2*c+1][0], e[2*c+1][1]);
                cvt.u[3] = pkh(e[2*c+1][2], e[2*c+1][3]);
                pB[c] = cvt.hv;
            }

            #pragma unroll
            for (int nt = 0; nt < 4; ++nt) {
                o[gq][nt] = __builtin_amdgcn_mfma_f32_16x16x32_f16(vA[nt][0], pB[0], o[gq][nt], 0, 0, 0);
                o[gq][nt] = __builtin_amdgcn_mfma_f32_16x16x32_f16(vA[nt][1], pB[1], o[gq][nt], 0, 0, 0);
            }
            // l per q-row via ones-row MFMA on the SAME packed P
            lD[gq] = __builtin_amdgcn_mfma_f32_16x16x32_f16(ones, pB[0], lD[gq], 0, 0, 0);
            lD[gq] = __builtin_amdgcn_mfma_f32_16x16x32_f16(ones, pB[1], lD[gq], 0, 0, 0);
        }
    };

    stage(0, 0);

    for (int ph = 0; ph < NPHASES; ++ph) {
        const int cur = ph & 1;
        __syncthreads();   // buf[cur] staged (vmcnt drained) + prev reads done

        if (ph + 1 < NPHASES) stage(ph + 1, cur ^ 1);

        const unsigned long long m00 = mr[0][2 * ph],     m01 = mr[1][2 * ph];
        const unsigned long long m10 = mr[0][2 * ph + 1], m11 = mr[1][2 * ph + 1];

        compute(&KV[cur][0][0],    &KV[cur][1][0],    m00, m01);
        compute(&KV[cur][0][4096], &KV[cur][1][4096], m10, m11);
    }

    #pragma unroll
    for (int gq = 0; gq < 2; ++gq) {
        const float inv = 1.0f / lD[gq][0];   // all 4 components identical
        const size_t row = (size_t)(b_ * S + qs + 16 * gq + a);
        #pragma unroll
        for (int nt = 0; nt < 4; ++nt) {
            union { unsigned u[2]; uint2 u2; } cvt;
            cvt.u[0] = pkh(o[gq][nt][0] * inv, o[gq][nt][1] * inv);
            cvt.u[1] = pkh(o[gq][nt][2] * inv, o[gq][nt][3] * inv);
            *(uint2*)(att + row * DM + h * 64 + 16 * nt + 4 * g) = cvt.u2;
        }
    }
}

// ---------------------------------------------------------------------------
// Kernel 3: output projection, single-term fp16 MFMA GEMM.
// C(8192x1024) = X(fp16) @ Wo(fp16)^T + bo. 128x128 tile, BK=64,
// global_load_lds + XOR gather swizzle, double-buffered (1 barrier/tile).
// ---------------------------------------------------------------------------
__global__ __launch_bounds__(256, 2) void out_proj_kernel(
    const half_t* __restrict__ X, const half_t* __restrict__ Wh,
    const float* __restrict__ bo, float* __restrict__ out)
{
    __shared__ half_t SA[2][128 * 64], SB[2][128 * 64];   // 64 KB total

    const int tid = threadIdx.x;
    const int w = tid >> 6, L = tid & 63, a = L & 15, g = L >> 4;
    const int wm = w >> 1, wn = w & 1;
    const int r0 = blockIdx.x * 128;
    const int n0 = blockIdx.y * 128;

    int prow[4], pchk[4], pbase[4];
    #pragma unroll
    for (int i = 0; i < 4; ++i) {
        int p    = w * 256 + i * 64 + L;
        prow[i]  = p >> 3;
        pchk[i]  = (p & 7) ^ (prow[i] & 7);
        pbase[i] = (w * 256 + i * 64) * 8;   // fp16-element offset of wave base
    }

    const float4v z4 = {0.0f, 0.0f, 0.0f, 0.0f};
    float4v acc[4][4];
    #pragma unroll
    for (int mt = 0; mt < 4; ++mt)
        #pragma unroll
        for (int nt = 0; nt < 4; ++nt) acc[mt][nt] = z4;

    // stage k-tile 0 into buf 0
    #pragma unroll
    for (int i = 0; i < 4; ++i) {
        gl2lds16(X  + (size_t)(r0 + prow[i]) * DM + pchk[i] * 8, &SA[0][pbase[i]]);
        gl2lds16(Wh + (size_t)(n0 + prow[i]) * DM + pchk[i] * 8, &SB[0][pbase[i]]);
    }

    for (int kt = 0; kt < DM / 64; ++kt) {
        const int cur = kt & 1;
        __syncthreads();   // buf[cur] staged + prev frag reads done

        if (kt + 1 < DM / 64) {
            const int k0 = (kt + 1) * 64;
            #pragma unroll
            for (int i = 0; i < 4; ++i) {
                gl2lds16(X  + (size_t)(r0 + prow[i]) * DM + k0 + pchk[i] * 8, &SA[cur ^ 1][pbase[i]]);
                gl2lds16(Wh + (size_t)(n0 + prow[i]) * DM + k0 + pchk[i] * 8, &SB[cur ^ 1][pbase[i]]);
            }
        }

        half8v bF[4][2];
        #pragma unroll
        for (int nt = 0; nt < 4; ++nt)
            #pragma unroll
            for (int c = 0; c < 2; ++c) {
                const int rb  = 64 * wn + 16 * nt + a;
                const int off = (rb * 8 + ((4 * c + g) ^ (rb & 7))) * 8;
                bF[nt][c] = *(const half8v*)&SB[cur][off];
            }

        #pragma unroll
        for (int mt = 0; mt < 4; ++mt) {
            const int ra   = 64 * wm + 16 * mt + a;
            const int off0 = (ra * 8 + ((0 + g) ^ (ra & 7))) * 8;
            const int off1 = (ra * 8 + ((4 + g) ^ (ra & 7))) * 8;
            half8v a0 = *(const half8v*)&SA[cur][off0];
            half8v a1 = *(const half8v*)&SA[cur][off1];
            #pragma unroll
            for (int nt = 0; nt < 4; ++nt) {
                float4v acv = acc[mt][nt];
                acv = __builtin_amdgcn_mfma_f32_16x16x32_f16(a0, bF[nt][0], acv, 0, 0, 0);
                acv = __builtin_amdgcn_mfma_f32_16x16x32_f16(a1, bF[nt][1], acv, 0, 0, 0);
                acc[mt][nt] = acv;
            }
        }
    }

    #pragma unroll
    for (int mt = 0; mt < 4; ++mt) {
        const int m0 = r0 + 64 * wm + 16 * mt + 4 * g;
        #pragma unroll
        for (int nt = 0; nt < 4; ++nt) {
            const int n = n0 + 64 * wn + 16 * nt + a;
            const float bias = bo[n];
            #pragma unroll
            for (int r = 0; r < 4; ++r)
                out[(size_t)(m0 + r) * DM + n] = acc[mt][nt][r] + bias;
        }
    }
}

// ---------------------------------------------------------------------------
extern "C" void kernel_launch(void* const* d_in, const int* in_sizes, int n_in,
                              void* d_out, int out_size, void* d_ws, size_t ws_size,
                              hipStream_t stream) {
    (void)in_sizes; (void)n_in; (void)out_size; (void)ws_size;
    const float* values = (const float*)d_in[0];
    const float* keys   = (const float*)d_in[1];
    const float* query  = (const float*)d_in[2];
    const int*   mask   = (const int*)d_in[3];
    const float* Wv     = (const float*)d_in[4];
    const float* Wk     = (const float*)d_in[5];
    const float* Wq     = (const float*)d_in[6];
    const float* Wo     = (const float*)d_in[7];
    const float* bo     = (const float*)d_in[8];
    float* out = (float*)d_out;

    const size_t per = (size_t)B * H * S * DK;     // 8,388,608 elements
    half_t* qw  = (half_t*)d_ws;
    half_t* kw  = qw + per;
    half_t* vtw = kw + per;
    unsigned long long* mp = (unsigned long long*)(vtw + per);
    half_t* atth = (half_t*)(mp + (size_t)S * S / 64);
    half_t* woh  = atth + per;                     // B*S*DM == per

    prep_kernel<<<MASK_BLOCKS + DM * DM / 1024, 256, 0, stream>>>(mask, mp, Wo, woh);

    dim3 g1(B * H * (S / 64), 3);
    qkv_proj_kernel<<<g1, 256, 0, stream>>>(values, keys, query, Wv, Wk, Wq, vtw, kw, qw);

    dim3 g2(B * H, S / 256);   // x=bh -> blockId%8 = head%8 (XCD L2 locality)
    flash_attn_kernel<<<g2, 512, 0, stream>>>(qw, kw, vtw, mp, atth);

    dim3 g3(B * S / 128, DM / 128);
    out_proj_kernel<<<g3, 256, 0, stream>>>(atth, woh, bo, out);
}

// Round 5
// 323.390 us; speedup vs baseline: 1.1570x; 1.0055x over previous
//
#include <hip/hip_runtime.h>

#define B 4
#define S 2048
#define H 16
#define DK 64
#define DM 1024
#define NTILES (S / 64)
#define QSCALE 0.18033688011112042f   // 0.125 * log2(e); folded into Q projection

typedef _Float16 half_t;
typedef __attribute__((ext_vector_type(8))) _Float16 half8v;   // 8 fp16 = MFMA A/B frag
typedef __attribute__((ext_vector_type(2))) __fp16   fp16x2;   // builtin return type
typedef __attribute__((ext_vector_type(4))) float    float4v;  // MFMA C/D frag

// pack two fp32 -> fp16x2 RTZ in one v_cvt_pkrtz (bias cancels in softmax O/l)
__device__ __forceinline__ unsigned pkh(float lo, float hi) {
    union { fp16x2 h; unsigned u; } cvt;
    cvt.h = __builtin_amdgcn_cvt_pkrtz(lo, hi);
    return cvt.u;
}
__device__ __forceinline__ float fast_exp2(float x) {
#if __has_builtin(__builtin_amdgcn_exp2f)
    return __builtin_amdgcn_exp2f(x);
#else
    return __expf(x * 0.69314718055994531f);
#endif
}
// convert 8 fp32 (two float4, consecutive k) -> fp16 frag (RNE v_cvt_f16_f32)
__device__ __forceinline__ half8v cvt8h(float4 a, float4 b) {
    half8v r;
    r[0] = (half_t)a.x; r[1] = (half_t)a.y; r[2] = (half_t)a.z; r[3] = (half_t)a.w;
    r[4] = (half_t)b.x; r[5] = (half_t)b.y; r[6] = (half_t)b.z; r[7] = (half_t)b.w;
    return r;
}
// async global -> LDS, 16B per lane. LDS dest = wave-uniform base + lane*16.
__device__ __forceinline__ void gl2lds16(const void* g, void* l) {
    __builtin_amdgcn_global_load_lds(
        (const __attribute__((address_space(1))) unsigned int*)g,
        (__attribute__((address_space(3))) unsigned int*)l, 16, 0, 0);
}

// ---------------------------------------------------------------------------
// Kernel 0: fused prep. Blocks [0, S*S/256): pack mask bits.
// Blocks [S*S/256, +DM*DM/1024): convert Wo fp32 -> fp16.
// ---------------------------------------------------------------------------
#define MASK_BLOCKS (S * S / 256)
__global__ __launch_bounds__(256) void prep_kernel(
    const int* __restrict__ mask, unsigned long long* __restrict__ mp,
    const float* __restrict__ Wo, half_t* __restrict__ Wh)
{
    int bx = blockIdx.x;
    if (bx < MASK_BLOCKS) {
        int t = bx * 256 + threadIdx.x;
        int m = mask[t];
        unsigned long long b = __ballot(m != 0);
        if ((threadIdx.x & 63) == 0) mp[t >> 6] = b;
    } else {
        int t = ((bx - MASK_BLOCKS) * 256 + threadIdx.x) * 4;
        float4 wv = *(const float4*)(Wo + t);
        union { half_t h[4]; uint2 u; } cvt;
        cvt.h[0] = (half_t)wv.x; cvt.h[1] = (half_t)wv.y;
        cvt.h[2] = (half_t)wv.z; cvt.h[3] = (half_t)wv.w;
        *(uint2*)(Wh + t) = cvt.u;
    }
}

// ---------------------------------------------------------------------------
// Kernel 1: QKV projection via fp16 MFMA. Output bounced through padded LDS
// tile (stride 72: 16B-aligned rows, bank-spread) -> two 16B global stores
// per lane instead of 16 scalar 2B stores.
// y=0: V -> Vt (B,H,64,S) with PV-permuted columns; y=1: K; y=2: Q (scaled).
// ---------------------------------------------------------------------------
#define QSTR 72   // LDS bounce-tile stride (halves): 144B rows, 16B aligned
__global__ __launch_bounds__(256) void qkv_proj_kernel(
    const float* __restrict__ xv, const float* __restrict__ xk, const float* __restrict__ xq,
    const float* __restrict__ Wv, const float* __restrict__ Wk, const float* __restrict__ Wq,
    half_t* __restrict__ vtw, half_t* __restrict__ kw, half_t* __restrict__ qw)
{
    __shared__ half_t Ls[64 * QSTR];

    const int y = blockIdx.y;
    const float* x; const float* W;
    if (y == 0)      { x = xv; W = Wv; }
    else if (y == 1) { x = xk; W = Wk; }
    else             { x = xq; W = Wq; }

    const int tid = threadIdx.x;
    const int w = tid >> 6, L = tid & 63, a = L & 15, g = L >> 4;
    const int bx  = blockIdx.x;
    const int st  = bx & 31;
    const int bh  = bx >> 5;
    const int b_  = bh >> 4, h = bh & 15;
    const int s0b = st * 64;

    // W fragments: lane a <-> dim-row 16t+a, quad g <-> k-chunk
    half8v wF[4][2];
    #pragma unroll
    for (int t = 0; t < 4; ++t)
        #pragma unroll
        for (int c = 0; c < 2; ++c) {
            const float* wr = W + (size_t)(16 * t + a) * 64 + 32 * c + 8 * g;
            wF[t][c] = cvt8h(*(const float4*)wr, *(const float4*)(wr + 4));
        }

    // x fragments: lane a <-> s-row s0b+16w+a
    const float* xr = x + ((size_t)(b_ * S) + s0b + 16 * w + a) * DM + h * 64 + 8 * g;
    half8v xF0 = cvt8h(*(const float4*)(xr),      *(const float4*)(xr + 4));
    half8v xF1 = cvt8h(*(const float4*)(xr + 32), *(const float4*)(xr + 36));

    const float4v z4 = {0.0f, 0.0f, 0.0f, 0.0f};

    if (y == 0) {
        // V^T: A = W (m=d), B = x (n=s). D[m=4g+r][n=a]. Ls[d][pos]
        const int c   = 16 * w + a;
        const int pos = 32 * (c >> 5) + 8 * ((c >> 2) & 3) + 4 * ((c >> 4) & 1) + (c & 3);
        #pragma unroll
        for (int mt = 0; mt < 4; ++mt) {
            float4v D = __builtin_amdgcn_mfma_f32_16x16x32_f16(wF[mt][0], xF0, z4, 0, 0, 0);
            D = __builtin_amdgcn_mfma_f32_16x16x32_f16(wF[mt][1], xF1, D, 0, 0, 0);
            #pragma unroll
            for (int r = 0; r < 4; ++r)
                Ls[(16 * mt + 4 * g + r) * QSTR + pos] = (half_t)D[r];
        }
    } else {
        const float scale = (y == 2) ? QSCALE : 1.0f;
        #pragma unroll
        for (int nt = 0; nt < 4; ++nt) {
            float4v D = __builtin_amdgcn_mfma_f32_16x16x32_f16(xF0, wF[nt][0], z4, 0, 0, 0);
            D = __builtin_amdgcn_mfma_f32_16x16x32_f16(xF1, wF[nt][1], D, 0, 0, 0);
            #pragma unroll
            for (int r = 0; r < 4; ++r)
                Ls[(16 * w + 4 * g + r) * QSTR + 16 * nt + a] = (half_t)(D[r] * scale);
        }
    }
    __syncthreads();

    // coalesced copy-out: each thread 16 halves (two 16B stores), 4 threads/row
    const int row = tid >> 2;
    const int col = (tid & 3) * 16;
    uint4 v0 = *(const uint4*)&Ls[row * QSTR + col];
    uint4 v1 = *(const uint4*)&Ls[row * QSTR + col + 8];
    half_t* dst;
    if (y == 0)      dst = vtw + ((size_t)bh * 64 + row) * S + s0b + col;
    else {
        half_t* out = (y == 1) ? kw : qw;
        dst = out + ((size_t)bh * S + s0b + row) * 64 + col;
    }
    *(uint4*)dst = v0;
    *(uint4*)(dst + 8) = v1;
}

// ---------------------------------------------------------------------------
// Kernel 2: flash attention, fp16 MFMA. Round-0 verified body bit-identical,
// but 256 THREADS / 4 waves / 128 q-rows per block -> grid 1024 blocks.
// Occupancy: LDS 32 KB + VGPR ~76 -> ~5 blocks/CU (20 waves/CU), waves on a
// SIMD come from DIFFERENT blocks at different phases: desynchronized
// barriers fill the dependency-chain gaps that lockstep 2-block/CU couldn't.
// K/V staged via global_load_lds + XOR gather swizzle, double-buffered.
// ---------------------------------------------------------------------------
__global__ __launch_bounds__(256) void flash_attn_kernel(
    const half_t* __restrict__ q, const half_t* __restrict__ k,
    const half_t* __restrict__ vt, const unsigned long long* __restrict__ mp,
    half_t* __restrict__ att)
{
    __shared__ half_t KV[2][2][64 * 64];  // [buf][0=K,1=V] = 32 KB

    const int tid = threadIdx.x;
    const int w   = tid >> 6;            // 0..3
    const int L   = tid & 63;
    const int a   = L & 15;
    const int g   = L >> 4;
    const int bh  = blockIdx.x;
    const int b_  = bh >> 4, h = bh & 15;
    const int qs  = blockIdx.y * 128 + w * 32;   // wave's 32 q-rows

    const half_t* qb = q  + (size_t)bh * S * 64;
    const half_t* kb = k  + (size_t)bh * S * 64;
    const half_t* vb = vt + (size_t)bh * 64 * S;

    half8v qB[2][2];
    #pragma unroll
    for (int gq = 0; gq < 2; ++gq) {
        const half_t* qr = qb + (size_t)(qs + 16 * gq + a) * 64;
        qB[gq][0] = *(const half8v*)(qr +      g * 8);
        qB[gq][1] = *(const half8v*)(qr + 32 + g * 8);
    }

    const unsigned long long* mr[2];
    #pragma unroll
    for (int gq = 0; gq < 2; ++gq)
        mr[gq] = mp + (size_t)(qs + 16 * gq + a) * NTILES;

    // staging: 256 lanes, 2 gl2lds16 per matrix per tile (rows 0-31, 32-63).
    // chunk index c = i*256 + p; srow = i*32 + (p>>3); slot = c&7 = p&7;
    // schk = slot ^ (srow&7) and (srow&7) == ((p>>3)&7) since 32 = 0 mod 8.
    const int p     = tid;              // 0..255
    const int srow0 = p >> 3;           // 0..31
    const int schk  = (p & 7) ^ (srow0 & 7);
    const size_t kgo = (size_t)srow0 * 64 + schk * 8;  // + i*2048 + kt*4096
    const size_t vgo = (size_t)srow0 * S  + schk * 8;  // + i*32*S  + kt*64

    half8v ones;
    #pragma unroll
    for (int i = 0; i < 8; ++i) ones[i] = (half_t)1.0f;

    const float4v z4 = {0.0f, 0.0f, 0.0f, 0.0f};
    float4v o[2][4] = {{z4, z4, z4, z4}, {z4, z4, z4, z4}};
    float4v lD[2] = {z4, z4};

    auto stage = [&](int kt, int buf) {
        const size_t kr = (size_t)kt * 4096;   // element offset of k-tile rows
        const size_t vc = (size_t)kt * 64;     // column offset in V^T
        gl2lds16(kb + kr + kgo,            &KV[buf][0][       w * 512]);
        gl2lds16(kb + kr + 2048 + kgo,     &KV[buf][0][2048 + w * 512]);
        gl2lds16(vb + vc + vgo,            &KV[buf][1][       w * 512]);
        gl2lds16(vb + vc + (size_t)32 * S + vgo, &KV[buf][1][2048 + w * 512]);
    };

    stage(0, 0);

    for (int kt = 0; kt < NTILES; ++kt) {
        const int cur = kt & 1;
        __syncthreads();   // buf[cur] staged (vmcnt drained) + prev reads done

        if (kt + 1 < NTILES) stage(kt + 1, cur ^ 1);

        unsigned long long mw[2];
        #pragma unroll
        for (int gq = 0; gq < 2; ++gq) mw[gq] = mr[gq][kt];

        const half_t* Kb = &KV[cur][0][0];
        const half_t* Vb = &KV[cur][1][0];

        half8v kB[4][2], vA[4][2];
        #pragma unroll
        for (int nt = 0; nt < 4; ++nt)
            #pragma unroll
            for (int c = 0; c < 2; ++c) {
                const int off = ((16 * nt + a) * 8 + ((4 * c + g) ^ (a & 7))) * 8;
                kB[nt][c] = *(const half8v*)(Kb + off);
                vA[nt][c] = *(const half8v*)(Vb + off);
            }

        #pragma unroll
        for (int gq = 0; gq < 2; ++gq) {
            float4v st[4];
            #pragma unroll
            for (int nt = 0; nt < 4; ++nt) {
                st[nt] = __builtin_amdgcn_mfma_f32_16x16x32_f16(kB[nt][0], qB[gq][0], z4, 0, 0, 0);
                st[nt] = __builtin_amdgcn_mfma_f32_16x16x32_f16(kB[nt][1], qB[gq][1], st[nt], 0, 0, 0);
            }

            float e[4][4];
            #pragma unroll
            for (int nt = 0; nt < 4; ++nt) {
                unsigned bnt = (unsigned)(mw[gq] >> (16 * nt + 4 * g));
                #pragma unroll
                for (int r = 0; r < 4; ++r) {
                    float ee = fast_exp2(st[nt][r]);       // single v_exp_f32
                    e[nt][r] = ((bnt >> r) & 1u) ? ee : 0.0f;
                }
            }

            half8v pB[2];
            #pragma unroll
            for (int c = 0; c < 2; ++c) {
                union { unsigned u[4]; half8v hv; } cvt;
                cvt.u[0] = pkh(e[2*c  ][0], e[2*c  ][1]);
                cvt.u[1] = pkh(e[2*c  ][2], e[2*c  ][3]);
                cvt.u[2] = pkh(e[2*c+1][0], e[2*c+1][1]);
                cvt.u[3] = pkh(e[2*c+1][2], e[2*c+1][3]);
                pB[c] = cvt.hv;
            }

            #pragma unroll
            for (int nt = 0; nt < 4; ++nt) {
                o[gq][nt] = __builtin_amdgcn_mfma_f32_16x16x32_f16(vA[nt][0], pB[0], o[gq][nt], 0, 0, 0);
                o[gq][nt] = __builtin_amdgcn_mfma_f32_16x16x32_f16(vA[nt][1], pB[1], o[gq][nt], 0, 0, 0);
            }
            // l per q-row via ones-row MFMA on the SAME packed P
            lD[gq] = __builtin_amdgcn_mfma_f32_16x16x32_f16(ones, pB[0], lD[gq], 0, 0, 0);
            lD[gq] = __builtin_amdgcn_mfma_f32_16x16x32_f16(ones, pB[1], lD[gq], 0, 0, 0);
        }
    }

    #pragma unroll
    for (int gq = 0; gq < 2; ++gq) {
        const float inv = 1.0f / lD[gq][0];   // all 4 components identical
        const size_t row = (size_t)(b_ * S + qs + 16 * gq + a);
        #pragma unroll
        for (int nt = 0; nt < 4; ++nt) {
            union { unsigned u[2]; uint2 u2; } cvt;
            cvt.u[0] = pkh(o[gq][nt][0] * inv, o[gq][nt][1] * inv);
            cvt.u[1] = pkh(o[gq][nt][2] * inv, o[gq][nt][3] * inv);
            *(uint2*)(att + row * DM + h * 64 + 16 * nt + 4 * g) = cvt.u2;
        }
    }
}

// ---------------------------------------------------------------------------
// Kernel 3: output projection, single-term fp16 MFMA GEMM.
// C(8192x1024) = X(fp16) @ Wo(fp16)^T + bo. 128x128 tile, BK=64,
// global_load_lds + XOR gather swizzle, double-buffered (1 barrier/tile).
// ---------------------------------------------------------------------------
__global__ __launch_bounds__(256, 2) void out_proj_kernel(
    const half_t* __restrict__ X, const half_t* __restrict__ Wh,
    const float* __restrict__ bo, float* __restrict__ out)
{
    __shared__ half_t SA[2][128 * 64], SB[2][128 * 64];   // 64 KB total

    const int tid = threadIdx.x;
    const int w = tid >> 6, L = tid & 63, a = L & 15, g = L >> 4;
    const int wm = w >> 1, wn = w & 1;
    const int r0 = blockIdx.x * 128;
    const int n0 = blockIdx.y * 128;

    int prow[4], pchk[4], pbase[4];
    #pragma unroll
    for (int i = 0; i < 4; ++i) {
        int p    = w * 256 + i * 64 + L;
        prow[i]  = p >> 3;
        pchk[i]  = (p & 7) ^ (prow[i] & 7);
        pbase[i] = (w * 256 + i * 64) * 8;   // fp16-element offset of wave base
    }

    const float4v z4 = {0.0f, 0.0f, 0.0f, 0.0f};
    float4v acc[4][4];
    #pragma unroll
    for (int mt = 0; mt < 4; ++mt)
        #pragma unroll
        for (int nt = 0; nt < 4; ++nt) acc[mt][nt] = z4;

    // stage k-tile 0 into buf 0
    #pragma unroll
    for (int i = 0; i < 4; ++i) {
        gl2lds16(X  + (size_t)(r0 + prow[i]) * DM + pchk[i] * 8, &SA[0][pbase[i]]);
        gl2lds16(Wh + (size_t)(n0 + prow[i]) * DM + pchk[i] * 8, &SB[0][pbase[i]]);
    }

    for (int kt = 0; kt < DM / 64; ++kt) {
        const int cur = kt & 1;
        __syncthreads();   // buf[cur] staged + prev frag reads done

        if (kt + 1 < DM / 64) {
            const int k0 = (kt + 1) * 64;
            #pragma unroll
            for (int i = 0; i < 4; ++i) {
                gl2lds16(X  + (size_t)(r0 + prow[i]) * DM + k0 + pchk[i] * 8, &SA[cur ^ 1][pbase[i]]);
                gl2lds16(Wh + (size_t)(n0 + prow[i]) * DM + k0 + pchk[i] * 8, &SB[cur ^ 1][pbase[i]]);
            }
        }

        half8v bF[4][2];
        #pragma unroll
        for (int nt = 0; nt < 4; ++nt)
            #pragma unroll
            for (int c = 0; c < 2; ++c) {
                const int rb  = 64 * wn + 16 * nt + a;
                const int off = (rb * 8 + ((4 * c + g) ^ (rb & 7))) * 8;
                bF[nt][c] = *(const half8v*)&SB[cur][off];
            }

        #pragma unroll
        for (int mt = 0; mt < 4; ++mt) {
            const int ra   = 64 * wm + 16 * mt + a;
            const int off0 = (ra * 8 + ((0 + g) ^ (ra & 7))) * 8;
            const int off1 = (ra * 8 + ((4 + g) ^ (ra & 7))) * 8;
            half8v a0 = *(const half8v*)&SA[cur][off0];
            half8v a1 = *(const half8v*)&SA[cur][off1];
            #pragma unroll
            for (int nt = 0; nt < 4; ++nt) {
                float4v acv = acc[mt][nt];
                acv = __builtin_amdgcn_mfma_f32_16x16x32_f16(a0, bF[nt][0], acv, 0, 0, 0);
                acv = __builtin_amdgcn_mfma_f32_16x16x32_f16(a1, bF[nt][1], acv, 0, 0, 0);
                acc[mt][nt] = acv;
            }
        }
    }

    #pragma unroll
    for (int mt = 0; mt < 4; ++mt) {
        const int m0 = r0 + 64 * wm + 16 * mt + 4 * g;
        #pragma unroll
        for (int nt = 0; nt < 4; ++nt) {
            const int n = n0 + 64 * wn + 16 * nt + a;
            const float bias = bo[n];
            #pragma unroll
            for (int r = 0; r < 4; ++r)
                out[(size_t)(m0 + r) * DM + n] = acc[mt][nt][r] + bias;
        }
    }
}

// ---------------------------------------------------------------------------
extern "C" void kernel_launch(void* const* d_in, const int* in_sizes, int n_in,
                              void* d_out, int out_size, void* d_ws, size_t ws_size,
                              hipStream_t stream) {
    (void)in_sizes; (void)n_in; (void)out_size; (void)ws_size;
    const float* values = (const float*)d_in[0];
    const float* keys   = (const float*)d_in[1];
    const float* query  = (const float*)d_in[2];
    const int*   mask   = (const int*)d_in[3];
    const float* Wv     = (const float*)d_in[4];
    const float* Wk     = (const float*)d_in[5];
    const float* Wq     = (const float*)d_in[6];
    const float* Wo     = (const float*)d_in[7];
    const float* bo     = (const float*)d_in[8];
    float* out = (float*)d_out;

    const size_t per = (size_t)B * H * S * DK;     // 8,388,608 elements
    half_t* qw  = (half_t*)d_ws;
    half_t* kw  = qw + per;
    half_t* vtw = kw + per;
    unsigned long long* mp = (unsigned long long*)(vtw + per);
    half_t* atth = (half_t*)(mp + (size_t)S * S / 64);
    half_t* woh  = atth + per;                     // B*S*DM == per

    prep_kernel<<<MASK_BLOCKS + DM * DM / 1024, 256, 0, stream>>>(mask, mp, Wo, woh);

    dim3 g1(B * H * (S / 64), 3);
    qkv_proj_kernel<<<g1, 256, 0, stream>>>(values, keys, query, Wv, Wk, Wq, vtw, kw, qw);

    dim3 g2(B * H, S / 128);   // 1024 blocks: 4 waves x 32 q-rows each
    flash_attn_kernel<<<g2, 256, 0, stream>>>(qw, kw, vtw, mp, atth);

    dim3 g3(B * S / 128, DM / 128);
    out_proj_kernel<<<g3, 256, 0, stream>>>(atth, woh, bo, out);
}